// Round 2
// baseline (949.734 us; speedup 1.0000x reference)
//
#include <hip/hip_runtime.h>

typedef unsigned short u16;
typedef float f32x4 __attribute__((ext_vector_type(4)));
typedef short bf16x8 __attribute__((ext_vector_type(8)));
typedef unsigned short u16x8 __attribute__((ext_vector_type(8)));

#define ND 768
#define KD 768

__device__ __forceinline__ float bf2f(u16 u) {
    union { unsigned i; float f; } v; v.i = ((unsigned)u) << 16; return v.f;
}
__device__ __forceinline__ u16 f2bf(float f) {
    union { float f; unsigned u; } x; x.f = f;
    unsigned r = x.u + 0x7fffu + ((x.u >> 16) & 1u);
    return (u16)(r >> 16);
}
__device__ __forceinline__ void async16(const void* g, void* l) {
    __builtin_amdgcn_global_load_lds((const __attribute__((address_space(1))) void*)g,
                                     (__attribute__((address_space(3))) void*)l, 16, 0, 0);
}

// ---- transpose+convert weights via LDS tiles: Wt[m][n][k] = bf16(W_m[k][n]) ----
// grid: 5 mats * 12*12 tiles of 64x64 = 720 blocks
__global__ __launch_bounds__(256) void conv_w(const float* __restrict__ W_emb,
                                              const float* __restrict__ gat_W,
                                              const float* __restrict__ W_out,
                                              u16* __restrict__ Wt)
{
    __shared__ float lds[64][65];
    const int m  = blockIdx.x / 144;
    const int r  = blockIdx.x % 144;
    const int tr = r / 12;            // k-tile
    const int tc = r % 12;            // n-tile
    const float* src = (m == 0) ? W_emb : (m <= 3) ? (gat_W + (size_t)(m - 1) * 589824) : W_out;
    const int c  = threadIdx.x & 63;
    const int w4 = threadIdx.x >> 6;  // 0..3
    #pragma unroll
    for (int i = 0; i < 16; ++i) {
        int kk = i * 4 + w4;
        lds[kk][c] = src[(size_t)(tr * 64 + kk) * 768 + tc * 64 + c];
    }
    __syncthreads();
    u16* dst = Wt + (size_t)m * 589824;
    #pragma unroll
    for (int i = 0; i < 16; ++i) {
        int nn = i * 4 + w4;
        dst[(size_t)(tc * 64 + nn) * 768 + tr * 64 + c] = f2bf(lds[c][nn]);
    }
}

// ---- fp32 -> bf16 bulk convert ----
__global__ __launch_bounds__(256) void conv_x(const float4* __restrict__ in,
                                              u16* __restrict__ outp, int n4)
{
    for (int i = blockIdx.x * 256 + threadIdx.x; i < n4; i += gridDim.x * 256) {
        float4 v = in[i];
        union { u16 s[4]; uint2 u; } o;
        o.s[0] = f2bf(v.x); o.s[1] = f2bf(v.y); o.s[2] = f2bf(v.z); o.s[3] = f2bf(v.w);
        ((uint2*)outp)[i] = o.u;
    }
}

// ---- m97-style bf16 GEMM: C[m][n] = sum_k A[m][k] * Bt[n][k] (+bias) ----
// A: (57344 x 768) bf16, Bt: (768 x 768) bf16 (transposed weights, K-major)
// grid 2688 (XCD-chunk-swizzled -> 6 x 448), block 256 (4 waves, 2x2 of 64x64)
template<bool F32OUT>
__global__ __launch_bounds__(256) void gemm_bt(const u16* __restrict__ A,
                                               const u16* __restrict__ Bt,
                                               const float* __restrict__ bias,
                                               void* __restrict__ Cout)
{
    __shared__ u16 lA[128 * 32];
    __shared__ u16 lB[128 * 32];
    const int tid  = threadIdx.x;
    const int lane = tid & 63;
    const int wvb  = tid & ~63;              // wave*64
    const int wm   = ((tid >> 7) & 1) * 64;  // wave row block
    const int wn   = ((tid >> 6) & 1) * 64;  // wave col block
    // XCD-chunked bijective swizzle: 2688 = 8 * 336; col-blocks of one row
    // panel become consecutive within one XCD chunk -> A panel L2-shared.
    const int wg = blockIdx.x;
    const int id = (wg & 7) * 336 + (wg >> 3);
    const int tn = (id % 6) * 128;
    const int tm = (id / 6) * 128;

    f32x4 acc[4][4] = {};

    const int lr = lane & 15;
    const int lk = (lane >> 4) << 3;

    for (int ks = 0; ks < KD / 32; ++ks) {
        const int k0 = ks * 32;
        #pragma unroll
        for (int it = 0; it < 2; ++it) {
            int c   = tid + it * 256;        // chunk id 0..511
            int row = c >> 2;                // 4 chunks of 8 bf16 per row (BK=32)
            int kc  = (c & 3) << 3;
            async16(A + (size_t)(tm + row) * KD + (k0 + kc),
                    &lA[(size_t)(it * 256 + wvb) * 8]);
            async16(Bt + (size_t)(tn + row) * KD + (k0 + kc),
                    &lB[(size_t)(it * 256 + wvb) * 8]);
        }
        __syncthreads();   // drains vmcnt(0)

        bf16x8 af[4], bf[4];
        #pragma unroll
        for (int mi = 0; mi < 4; ++mi)
            af[mi] = *(const bf16x8*)&lA[(wm + mi * 16 + lr) * 32 + lk];
        #pragma unroll
        for (int ni = 0; ni < 4; ++ni)
            bf[ni] = *(const bf16x8*)&lB[(wn + ni * 16 + lr) * 32 + lk];
        #pragma unroll
        for (int mi = 0; mi < 4; ++mi)
            #pragma unroll
            for (int ni = 0; ni < 4; ++ni)
                acc[mi][ni] = __builtin_amdgcn_mfma_f32_16x16x32_bf16(
                    af[mi], bf[ni], acc[mi][ni], 0, 0, 0);
        __syncthreads();
    }

    // epilogue: C/D layout col=lane&15, row=(lane>>4)*4+reg
    const int lr4 = (lane >> 4) << 2;
    #pragma unroll
    for (int ni = 0; ni < 4; ++ni) {
        int col = tn + wn + ni * 16 + lr;
        float bv = bias ? bias[col] : 0.0f;
        #pragma unroll
        for (int mi = 0; mi < 4; ++mi) {
            int rowb = tm + wm + mi * 16 + lr4;
            #pragma unroll
            for (int r = 0; r < 4; ++r) {
                float v = acc[mi][ni][r] + bv;
                if (F32OUT)
                    ((float*)Cout)[(size_t)(rowb + r) * ND + col] = v;
                else
                    ((u16*)Cout)[(size_t)(rowb + r) * ND + col] = f2bf(v);
            }
        }
    }
}

// ---- fused GAT attention per batch ----
// STAGE=true: stage Wh slice in LDS (required when Xout aliases Wh).
// STAGE=false: read Wh from global (L1-resident 21.5KB slice), tiny LDS.
template<bool STAGE, bool ELU>
__global__ __launch_bounds__(256) void gat_attn(const u16* __restrict__ Wh,
                                                const float* __restrict__ adj,
                                                const float* __restrict__ avec,
                                                float* __restrict__ attn_out,
                                                u16* __restrict__ Xout)
{
    __shared__ float s_ei[14], s_ej[14];
    __shared__ float s_attn[196];
    __shared__ u16 wh[STAGE ? 14 * 768 : 8];
    const int b = blockIdx.x;
    const int tid = threadIdx.x;
    const int lane = tid & 63, wave = tid >> 6;
    const u16* whb = Wh + (size_t)b * 10752;

    if (STAGE) {
        for (int c = tid; c < 1344; c += 256)
            ((uint4*)wh)[c] = ((const uint4*)whb)[c];
        __syncthreads();
    }

    // ei[i] = dot(Wh[i,:], a_i); ej[i] = dot(Wh[i,:], a_j)
    for (int i = wave; i < 14; i += 4) {
        float ai = 0.f, aj = 0.f;
        for (int d = lane; d < 768; d += 64) {
            float w = STAGE ? bf2f(wh[i * 768 + d]) : bf2f(whb[i * 768 + d]);
            ai += w * avec[d];
            aj += w * avec[768 + d];
        }
        #pragma unroll
        for (int off = 32; off > 0; off >>= 1) {
            ai += __shfl_down(ai, off);
            aj += __shfl_down(aj, off);
        }
        if (lane == 0) { s_ei[i] = ai; s_ej[i] = aj; }
    }
    __syncthreads();

    // masked softmax over j per row i (N=14, fp32)
    if (tid < 14) {
        const int i = tid;
        float e[14];
        float mx = -3.0e38f;
        #pragma unroll
        for (int j = 0; j < 14; ++j) {
            float ev = (adj[(size_t)b * 196 + i * 14 + j] > 0.f)
                           ? (s_ei[i] + s_ej[j]) : -1.0e30f;
            e[j] = ev; mx = fmaxf(mx, ev);
        }
        float sum = 0.f;
        #pragma unroll
        for (int j = 0; j < 14; ++j) { float p = __expf(e[j] - mx); e[j] = p; sum += p; }
        float inv = 1.0f / sum;
        #pragma unroll
        for (int j = 0; j < 14; ++j) s_attn[i * 14 + j] = e[j] * inv;
    }
    __syncthreads();
    if (tid < 196) attn_out[(size_t)b * 196 + tid] = s_attn[tid];

    // h[i,d] = sum_j attn[i,j] * Wh[j,d]; optional ELU; write bf16
    for (int p = tid; p < 14 * 96; p += 256) {
        const int i  = p / 96;
        const int d0 = (p % 96) * 8;
        float acc[8] = {};
        #pragma unroll
        for (int j = 0; j < 14; ++j) {
            float aw = s_attn[i * 14 + j];
            u16x8 wv = STAGE ? *(const u16x8*)&wh[j * 768 + d0]
                             : *(const u16x8*)&whb[j * 768 + d0];
            #pragma unroll
            for (int q = 0; q < 8; ++q) acc[q] += aw * bf2f(wv[q]);
        }
        union { u16 s[8]; uint4 u; } o;
        #pragma unroll
        for (int q = 0; q < 8; ++q) {
            float v = acc[q];
            if (ELU && v < 0.f) v = __expf(v) - 1.0f;
            o.s[q] = f2bf(v);
        }
        *(uint4*)&Xout[(size_t)b * 10752 + i * 768 + d0] = o.u;
    }
}

extern "C" void kernel_launch(void* const* d_in, const int* in_sizes, int n_in,
                              void* d_out, int out_size, void* d_ws, size_t ws_size,
                              hipStream_t stream)
{
    const float* features = (const float*)d_in[0];
    const float* adj      = (const float*)d_in[1];
    const float* W_emb    = (const float*)d_in[2];
    const float* b_emb    = (const float*)d_in[3];
    const float* gat_W    = (const float*)d_in[4];
    const float* gat_a    = (const float*)d_in[5];
    const float* W_out    = (const float*)d_in[6];
    const float* b_out    = (const float*)d_in[7];
    float* out = (float*)d_out;

    // workspace: Wh (bf16, 57344x768) + 5 transposed bf16 weight mats
    u16* Wh = (u16*)d_ws;
    u16* Wt = Wh + 44040192;
    // out-region used as two bf16 x ping-pong halves until the final GEMM
    u16* H0 = (u16*)d_out;
    u16* H1 = H0 + 44040192;
    float* attn0 = out + 44040192;
    float* attn1 = attn0 + 802816;
    float* attn2 = attn1 + 802816;

    conv_w<<<dim3(720), 256, 0, stream>>>(W_emb, gat_W, W_out, Wt);
    conv_x<<<dim3(4096), 256, 0, stream>>>((const float4*)features, H0, 11010048);

    dim3 gg(2688);
    // x0 = features @ W_emb + b_emb
    gemm_bt<false><<<gg, 256, 0, stream>>>(H0, Wt, b_emb, H1);
    // layer 0
    gemm_bt<false><<<gg, 256, 0, stream>>>(H1, Wt + 589824, nullptr, Wh);
    gat_attn<false, true><<<dim3(4096), 256, 0, stream>>>(Wh, adj, gat_a, attn0, H0);
    // layer 1
    gemm_bt<false><<<gg, 256, 0, stream>>>(H0, Wt + 2 * 589824, nullptr, Wh);
    gat_attn<false, true><<<dim3(4096), 256, 0, stream>>>(Wh, adj, gat_a + 1536, attn1, H1);
    // layer 2 (no ELU, x3 written in-place over Wh -> staged variant)
    gemm_bt<false><<<gg, 256, 0, stream>>>(H1, Wt + 3 * 589824, nullptr, Wh);
    gat_attn<true, false><<<dim3(4096), 256, 0, stream>>>(Wh, adj, gat_a + 3072, attn2, Wh);
    // out = x3 @ W_out + b_out (fp32)
    gemm_bt<true><<<gg, 256, 0, stream>>>(Wh, Wt + 4 * 589824, b_out, (void*)out);
}

// Round 3
// 733.304 us; speedup vs baseline: 1.2951x; 1.2951x over previous
//
#include <hip/hip_runtime.h>

typedef unsigned short u16;
typedef float f32x4 __attribute__((ext_vector_type(4)));
typedef short bf16x8 __attribute__((ext_vector_type(8)));
typedef unsigned short u16x8 __attribute__((ext_vector_type(8)));

#define ND 768
#define KD 768
#define NROW 57344

__device__ __forceinline__ float bf2f(u16 u) {
    union { unsigned i; float f; } v; v.i = ((unsigned)u) << 16; return v.f;
}
__device__ __forceinline__ u16 f2bf(float f) {
    union { float f; unsigned u; } x; x.f = f;
    unsigned r = x.u + 0x7fffu + ((x.u >> 16) & 1u);
    return (u16)(r >> 16);
}
__device__ __forceinline__ void async16(const void* g, void* l) {
    __builtin_amdgcn_global_load_lds((const __attribute__((address_space(1))) void*)g,
                                     (__attribute__((address_space(3))) void*)l, 16, 0, 0);
}

// ---- transpose+convert weights via LDS tiles: Wt[m][n][k] = bf16(W_m[k][n]) ----
__global__ __launch_bounds__(256) void conv_w(const float* __restrict__ W_emb,
                                              const float* __restrict__ gat_W,
                                              const float* __restrict__ W_out,
                                              u16* __restrict__ Wt)
{
    __shared__ float lds[64][65];
    const int m  = blockIdx.x / 144;
    const int r  = blockIdx.x % 144;
    const int tr = r / 12;            // k-tile
    const int tc = r % 12;            // n-tile
    const float* src = (m == 0) ? W_emb : (m <= 3) ? (gat_W + (size_t)(m - 1) * 589824) : W_out;
    const int c  = threadIdx.x & 63;
    const int w4 = threadIdx.x >> 6;
    #pragma unroll
    for (int i = 0; i < 16; ++i) {
        int kk = i * 4 + w4;
        lds[kk][c] = src[(size_t)(tr * 64 + kk) * 768 + tc * 64 + c];
    }
    __syncthreads();
    u16* dst = Wt + (size_t)m * 589824;
    #pragma unroll
    for (int i = 0; i < 16; ++i) {
        int nn = i * 4 + w4;
        dst[(size_t)(tc * 64 + nn) * 768 + tr * 64 + c] = f2bf(lds[c][nn]);
    }
}

// ---- fp32 -> bf16 bulk convert ----
__global__ __launch_bounds__(256) void conv_x(const float4* __restrict__ in,
                                              u16* __restrict__ outp, int n4)
{
    for (int i = blockIdx.x * 256 + threadIdx.x; i < n4; i += gridDim.x * 256) {
        float4 v = in[i];
        union { u16 s[4]; uint2 u; } o;
        o.s[0] = f2bf(v.x); o.s[1] = f2bf(v.y); o.s[2] = f2bf(v.z); o.s[3] = f2bf(v.w);
        ((uint2*)outp)[i] = o.u;
    }
}

// ---- bf16 GEMM: C[m][n] = sum_k A[m][k] * Bt[n][k] (+bias) ----
// Optional fused ei/ej epilogue: per-row 64-col partial dots with avec,
// written race-free to dots[24][57344] (slot = (tn>>6)|(wn>>6), +12 for ej).
template<bool F32OUT>
__global__ __launch_bounds__(256) void gemm_bt(const u16* __restrict__ A,
                                               const u16* __restrict__ Bt,
                                               const float* __restrict__ bias,
                                               void* __restrict__ Cout,
                                               const float* __restrict__ avec,
                                               float* __restrict__ dots)
{
    __shared__ u16 lA[128 * 32];
    __shared__ u16 lB[128 * 32];
    const int tid  = threadIdx.x;
    const int lane = tid & 63;
    const int wvb  = tid & ~63;
    const int wm   = ((tid >> 7) & 1) * 64;
    const int wn   = ((tid >> 6) & 1) * 64;
    // XCD-chunked bijective swizzle: 2688 = 8 * 336
    const int wg = blockIdx.x;
    const int id = (wg & 7) * 336 + (wg >> 3);
    const int tn = (id % 6) * 128;
    const int tm = (id / 6) * 128;

    f32x4 acc[4][4] = {};

    const int lr = lane & 15;
    const int lk = (lane >> 4) << 3;

    for (int ks = 0; ks < KD / 32; ++ks) {
        const int k0 = ks * 32;
        #pragma unroll
        for (int it = 0; it < 2; ++it) {
            int c   = tid + it * 256;
            int row = c >> 2;
            int kc  = (c & 3) << 3;
            async16(A + (size_t)(tm + row) * KD + (k0 + kc),
                    &lA[(size_t)(it * 256 + wvb) * 8]);
            async16(Bt + (size_t)(tn + row) * KD + (k0 + kc),
                    &lB[(size_t)(it * 256 + wvb) * 8]);
        }
        __syncthreads();

        bf16x8 af[4], bf[4];
        #pragma unroll
        for (int mi = 0; mi < 4; ++mi)
            af[mi] = *(const bf16x8*)&lA[(wm + mi * 16 + lr) * 32 + lk];
        #pragma unroll
        for (int ni = 0; ni < 4; ++ni)
            bf[ni] = *(const bf16x8*)&lB[(wn + ni * 16 + lr) * 32 + lk];
        #pragma unroll
        for (int mi = 0; mi < 4; ++mi)
            #pragma unroll
            for (int ni = 0; ni < 4; ++ni)
                acc[mi][ni] = __builtin_amdgcn_mfma_f32_16x16x32_bf16(
                    af[mi], bf[ni], acc[mi][ni], 0, 0, 0);
        __syncthreads();
    }

    const int lr4 = (lane >> 4) << 2;

    // fused ei/ej partial dots (GAT layers only)
    if (dots) {
        const int slot = (tn >> 6) | (wn >> 6);   // 0..11
        #pragma unroll
        for (int mi = 0; mi < 4; ++mi) {
            #pragma unroll
            for (int r = 0; r < 4; ++r) {
                float pi = 0.f, pj = 0.f;
                #pragma unroll
                for (int ni = 0; ni < 4; ++ni) {
                    int col = tn + wn + ni * 16 + lr;
                    float v = acc[mi][ni][r];
                    pi += v * avec[col];
                    pj += v * avec[768 + col];
                }
                #pragma unroll
                for (int off = 8; off; off >>= 1) {
                    pi += __shfl_xor(pi, off);
                    pj += __shfl_xor(pj, off);
                }
                if ((lane & 15) == 0) {
                    int row = tm + wm + mi * 16 + lr4 + r;
                    dots[(size_t)slot * NROW + row] = pi;
                    dots[(size_t)(12 + slot) * NROW + row] = pj;
                }
            }
        }
    }

    // C epilogue: C/D layout col=lane&15, row=(lane>>4)*4+reg
    #pragma unroll
    for (int ni = 0; ni < 4; ++ni) {
        int col = tn + wn + ni * 16 + lr;
        float bv = bias ? bias[col] : 0.0f;
        #pragma unroll
        for (int mi = 0; mi < 4; ++mi) {
            int rowb = tm + wm + mi * 16 + lr4;
            #pragma unroll
            for (int r = 0; r < 4; ++r) {
                float v = acc[mi][ni][r] + bv;
                if (F32OUT)
                    ((float*)Cout)[(size_t)(rowb + r) * ND + col] = v;
                else
                    ((u16*)Cout)[(size_t)(rowb + r) * ND + col] = f2bf(v);
            }
        }
    }
}

// ---- attention softmax + mix, LDS-staged (safe for Xout aliasing Wh) ----
template<bool ELU>
__global__ __launch_bounds__(256) void gat_mix(const u16* __restrict__ Wh,
                                               const float* __restrict__ adj,
                                               const float* __restrict__ dots,
                                               float* __restrict__ attn_out,
                                               u16* __restrict__ Xout)
{
    __shared__ u16 wh[14 * 768];
    __shared__ float s_attn[196];
    const int b = blockIdx.x;
    const int tid = threadIdx.x;
    const u16* whb = Wh + (size_t)b * 10752;

    for (int c = tid; c < 1344; c += 256)
        ((uint4*)wh)[c] = ((const uint4*)whb)[c];

    // threads 0..13: gather ei/ej partials + masked softmax (runs before barrier)
    if (tid < 14) {
        const int i = tid;
        float ei = 0.f;
        float ej[14];
        #pragma unroll
        for (int j = 0; j < 14; ++j) ej[j] = 0.f;
        #pragma unroll
        for (int s = 0; s < 12; ++s) {
            ei += dots[(size_t)s * NROW + b * 14 + i];
            #pragma unroll
            for (int j = 0; j < 14; ++j)
                ej[j] += dots[(size_t)(12 + s) * NROW + b * 14 + j];
        }
        float e[14];
        float mx = -3.0e38f;
        #pragma unroll
        for (int j = 0; j < 14; ++j) {
            float ev = (adj[(size_t)b * 196 + i * 14 + j] > 0.f) ? (ei + ej[j]) : -1.0e30f;
            e[j] = ev; mx = fmaxf(mx, ev);
        }
        float sum = 0.f;
        #pragma unroll
        for (int j = 0; j < 14; ++j) { float p = __expf(e[j] - mx); e[j] = p; sum += p; }
        float inv = 1.0f / sum;
        #pragma unroll
        for (int j = 0; j < 14; ++j) s_attn[i * 14 + j] = e[j] * inv;
    }
    __syncthreads();

    if (tid < 196) attn_out[(size_t)b * 196 + tid] = s_attn[tid];

    // mix: 16 output elems per item, h[i,d] = sum_j attn[i,j]*Wh[j,d], opt ELU
    for (int p = tid; p < 14 * 48; p += 256) {
        const int i  = p / 48;
        const int d0 = (p % 48) * 16;
        float acc[16] = {};
        #pragma unroll
        for (int j = 0; j < 14; ++j) {
            float aw = s_attn[i * 14 + j];
            u16x8 wv0 = *(const u16x8*)&wh[j * 768 + d0];
            u16x8 wv1 = *(const u16x8*)&wh[j * 768 + d0 + 8];
            #pragma unroll
            for (int q = 0; q < 8; ++q) {
                acc[q]     += aw * bf2f(wv0[q]);
                acc[8 + q] += aw * bf2f(wv1[q]);
            }
        }
        union { u16 s[16]; uint4 u[2]; } o;
        #pragma unroll
        for (int q = 0; q < 16; ++q) {
            float v = acc[q];
            if (ELU && v < 0.f) v = __expf(v) - 1.0f;
            o.s[q] = f2bf(v);
        }
        *(uint4*)&Xout[(size_t)b * 10752 + i * 768 + d0]     = o.u[0];
        *(uint4*)&Xout[(size_t)b * 10752 + i * 768 + d0 + 8] = o.u[1];
    }
}

extern "C" void kernel_launch(void* const* d_in, const int* in_sizes, int n_in,
                              void* d_out, int out_size, void* d_ws, size_t ws_size,
                              hipStream_t stream)
{
    const float* features = (const float*)d_in[0];
    const float* adj      = (const float*)d_in[1];
    const float* W_emb    = (const float*)d_in[2];
    const float* b_emb    = (const float*)d_in[3];
    const float* gat_W    = (const float*)d_in[4];
    const float* gat_a    = (const float*)d_in[5];
    const float* W_out    = (const float*)d_in[6];
    const float* b_out    = (const float*)d_in[7];
    float* out = (float*)d_out;

    // ws: Wh (bf16) | Wt (5 transposed bf16 mats) | dots (24 x 57344 f32)
    u16* Wh = (u16*)d_ws;
    u16* Wt = Wh + 44040192;
    float* dots = (float*)(Wt + 5 * 589824);
    // out-region used as two bf16 x ping-pong halves until the final GEMM
    u16* H0 = (u16*)d_out;
    u16* H1 = H0 + 44040192;
    float* attn0 = out + 44040192;
    float* attn1 = attn0 + 802816;
    float* attn2 = attn1 + 802816;

    conv_w<<<dim3(720), 256, 0, stream>>>(W_emb, gat_W, W_out, Wt);
    conv_x<<<dim3(4096), 256, 0, stream>>>((const float4*)features, H0, 11010048);

    dim3 gg(2688);
    // x0 = features @ W_emb + b_emb
    gemm_bt<false><<<gg, 256, 0, stream>>>(H0, Wt, b_emb, H1, nullptr, nullptr);
    // layer 0
    gemm_bt<false><<<gg, 256, 0, stream>>>(H1, Wt + 589824, nullptr, Wh, gat_a, dots);
    gat_mix<true><<<dim3(4096), 256, 0, stream>>>(Wh, adj, dots, attn0, H0);
    // layer 1
    gemm_bt<false><<<gg, 256, 0, stream>>>(H0, Wt + 2 * 589824, nullptr, Wh, gat_a + 1536, dots);
    gat_mix<true><<<dim3(4096), 256, 0, stream>>>(Wh, adj, dots, attn1, H1);
    // layer 2 (no ELU, x3 written in-place over Wh -> staged kernel is safe)
    gemm_bt<false><<<gg, 256, 0, stream>>>(H1, Wt + 3 * 589824, nullptr, Wh, gat_a + 3072, dots);
    gat_mix<false><<<dim3(4096), 256, 0, stream>>>(Wh, adj, dots, attn2, Wh);
    // out = x3 @ W_out + b_out (fp32)
    gemm_bt<true><<<gg, 256, 0, stream>>>(Wh, Wt + 4 * 589824, b_out, (void*)out, nullptr, nullptr);
}